// Round 11
// baseline (250.069 us; speedup 1.0000x reference)
//
#include <hip/hip_runtime.h>
#include <hip/hip_bf16.h>
#include <stdint.h>

// QuantumGeometricAttention — algebraic refactor:
//   G = Wm Wm^H folded into Wq (scores inner dim 128 real)
//   H = Wm Wmi  folded into Wo (PV inner dim 128 real)
// prep -> gh -> pack -> [QKV GEMM + V^T GEMM] -> flash attn (split-2, bf16 partials) -> out GEMM (fused merge).
// All MFMA LDS tiles use XOR-swizzle (chunk ^ ((row>>2)&3)) to kill the 8-way bank conflict
// of the [row][32shorts] layout while keeping global_load_lds staging contiguous.
// ws: 0 xn | 4MB WqkvT | 7MB Wbig | 9MB GH (+WmT) | 10MB QK bf16[4096][2048]
//     26MB Vt bf16[2048][2048] | 42MB Opart bf16[2][4096][1024] | 74MB Lpart f32[2][4096][8]

typedef __attribute__((ext_vector_type(8))) short bf16x8;
typedef __attribute__((ext_vector_type(4))) float f32x4;

#define QSCALE 0.18033688011112042f  /* 64^-0.5 * log2(e) */

__device__ __forceinline__ unsigned short f2b(float f) {
    union { float f; unsigned int u; } v; v.f = f;
    unsigned int r = v.u + 0x7fffu + ((v.u >> 16) & 1u);
    return (unsigned short)(r >> 16);
}

__device__ __forceinline__ float b2f(short s) {
    union { float f; unsigned int u; } v;
    v.u = ((unsigned int)(unsigned short)s) << 16;
    return v.f;
}

__device__ __forceinline__ unsigned int cvtpk(float a, float b) {
    union { __hip_bfloat162 h; unsigned int u; } v;
    v.h = __float22bfloat162_rn(make_float2(a, b));
    return v.u;
}

__device__ __forceinline__ void ld16(void* lds, const void* g) {
    __builtin_amdgcn_global_load_lds(
        (__attribute__((address_space(1))) unsigned int*)(g),
        (__attribute__((address_space(3))) unsigned int*)(lds), 16, 0, 0);
}

// ---------------- 1. prep: blocks 0..1023 = row L2-norm; 1024..1415 = fp32 transposes ----------------
__global__ __launch_bounds__(256) void k_prep(
        const float* __restrict__ x, unsigned short* __restrict__ xn,
        const float* __restrict__ s0, const float* __restrict__ s1,
        const float* __restrict__ s2, const float* __restrict__ s3,
        const float* __restrict__ s4, const float* __restrict__ s5,
        const float* __restrict__ s6, const float* __restrict__ s7,
        float* __restrict__ d0, float* __restrict__ d1,
        float* __restrict__ d2, float* __restrict__ d3,
        float* __restrict__ d4, float* __restrict__ d5,
        float* __restrict__ d6, float* __restrict__ d7) {
    __shared__ float tile[64][65];
    if (blockIdx.x < 1024) {
        int row  = blockIdx.x * 4 + (threadIdx.x >> 6);
        int lane = threadIdx.x & 63;
        const float4* xr = (const float4*)(x + (size_t)row * 512);
        float4 a = xr[lane], b = xr[lane + 64];
        float s = a.x*a.x + a.y*a.y + a.z*a.z + a.w*a.w
                + b.x*b.x + b.y*b.y + b.z*b.z + b.w*b.w;
        #pragma unroll
        for (int m = 1; m < 64; m <<= 1) s += __shfl_xor(s, m, 64);
        float inv = 1.0f / sqrtf(s);
        ushort4 o;
        o.x = f2b(a.x*inv); o.y = f2b(a.y*inv); o.z = f2b(a.z*inv); o.w = f2b(a.w*inv);
        *(ushort4*)&xn[(size_t)row*512 + lane*4] = o;
        o.x = f2b(b.x*inv); o.y = f2b(b.y*inv); o.z = f2b(b.z*inv); o.w = f2b(b.w*inv);
        *(ushort4*)&xn[(size_t)row*512 + 256 + lane*4] = o;
        return;
    }
    int bid = blockIdx.x - 1024;
    const float* src; float* dst; int R, C, tr, tc;
    if (bid < 384) {
        int mat = bid >> 6, tl = bid & 63;
        src = (mat==0)?s0:(mat==1)?s1:(mat==2)?s2:(mat==3)?s3:(mat==4)?s4:s5;
        dst = (mat==0)?d0:(mat==1)?d1:(mat==2)?d2:(mat==3)?d3:(mat==4)?d4:d5;
        R = 512; C = 512; tr = tl >> 3; tc = tl & 7;
    } else {
        int mat = (bid - 384) >> 2, tl = (bid - 384) & 3;
        src = mat ? s7 : s6; dst = mat ? d7 : d6;
        R = 64; C = 256; tr = 0; tc = tl;
    }
    int r0 = tr * 64, c0 = tc * 64;
    int tx = threadIdx.x & 63, ty = threadIdx.x >> 6;
    #pragma unroll
    for (int i = 0; i < 16; i++) {
        int r = ty + i*4;
        tile[r][tx] = src[(size_t)(r0 + r)*C + c0 + tx];
    }
    __syncthreads();
    #pragma unroll
    for (int i = 0; i < 16; i++) {
        int r = ty + i*4;
        dst[(size_t)(c0 + r)*R + r0 + tx] = tile[tx][r];
    }
}

// ---------------- 2. G = Wm Wm^H (row-major), Ht = (Wm Wmi)^T ----------------
__global__ __launch_bounds__(256) void k_gh(const float* __restrict__ Wm_re, const float* __restrict__ Wm_im,
                                            const float* __restrict__ WmT_re, const float* __restrict__ WmT_im,
                                            const float* __restrict__ Wmi_re, const float* __restrict__ Wmi_im,
                                            float* __restrict__ GH) {
    int id = blockIdx.x * 256 + threadIdx.x;   // 16384
    int mat = id >> 12;
    int a = (id >> 6) & 63, c = id & 63;       // a wave-uniform, c = lane
    float s = 0.f;
    if (mat < 2) {
        for (int m = 0; m < 256; m++) {
            float ar = Wm_re[a*256+m], ai = Wm_im[a*256+m];   // broadcast
            float br = WmT_re[m*64+c], bi = WmT_im[m*64+c];   // lane-contiguous
            s += (mat == 0) ? (ar*br + ai*bi) : (ai*br - ar*bi);
        }
        GH[id] = s;
    } else {
        for (int m = 0; m < 256; m++) {
            float ar = Wm_re[a*256+m], ai = Wm_im[a*256+m];
            float br = Wmi_re[m*64+c], bi = Wmi_im[m*64+c];
            s += (mat == 2) ? (ar*br - ai*bi) : (ar*bi + ai*br);
        }
        GH[mat*4096 + c*64 + a] = s;   // store H transposed
    }
}

// ---------------- 3. pack: blocks 0..6143 = WqkvT [3072][512]; 6144..10239 = Wbig [1024][1024] ----------------
__global__ __launch_bounds__(256) void k_pack(
        const float* __restrict__ WqT_re, const float* __restrict__ WqT_im,
        const float* __restrict__ WkT_re, const float* __restrict__ WkT_im,
        const float* __restrict__ WvT_re, const float* __restrict__ WvT_im,
        const float* __restrict__ Wo_re,  const float* __restrict__ Wo_im,
        const float* __restrict__ GH,
        unsigned short* __restrict__ WqkvT, unsigned short* __restrict__ Wbig) {
    if (blockIdx.x < 6144) {
        int id = blockIdx.x * 256 + threadIdx.x;
        int n = id >> 9, k = id & 511;             // n wave-uniform, k = lane
        float val;
        if (n < 1024) {
            int h = n >> 7, part = (n >> 6) & 1, j = n & 63;
            const float* Gr = GH;
            const float* Gi = GH + 4096;
            const float* qr = WqT_re + (size_t)(h*64)*512 + k;
            const float* qi = WqT_im + (size_t)(h*64)*512 + k;
            float s = 0.f;
            if (part == 0) { for (int d = 0; d < 64; d++) s += qr[d*512]*Gr[d*64+j] - qi[d*512]*Gi[d*64+j]; }
            else           { for (int d = 0; d < 64; d++) s += qr[d*512]*Gi[d*64+j] + qi[d*512]*Gr[d*64+j]; }
            val = s * QSCALE;
        } else if (n < 2048) {
            int m = n - 1024; int h = m >> 7, part = (m >> 6) & 1, j = m & 63;
            val = (part ? WkT_im : WkT_re)[(size_t)(h*64+j)*512 + k];
        } else {
            int m = n - 2048; int h = m >> 7, part = (m >> 6) & 1, j = m & 63;
            val = (part ? WvT_im : WvT_re)[(size_t)(h*64+j)*512 + k];
        }
        WqkvT[id] = f2b(val);
    } else {
        int id = (blockIdx.x - 6144) * 256 + threadIdx.x;
        int np = id >> 10, kk = id & 1023;         // np wave-uniform, lanes vary d
        int c = np >> 1, p = np & 1;
        int h = kk >> 7, pp = (kk >> 6) & 1, d = kk & 63;
        const float* HrT = GH + 2*4096;
        const float* HiT = GH + 3*4096;
        float s = 0.f;
        if (p == pp) {
            for (int j = 0; j < 64; j++) {
                float hr = HrT[j*64+d], hi = HiT[j*64+d];
                float wr = Wo_re[(size_t)(h*64+j)*512 + c];
                float wi = Wo_im[(size_t)(h*64+j)*512 + c];
                s += hr*wr - hi*wi;
            }
        } else {
            for (int j = 0; j < 64; j++) {
                float hr = HrT[j*64+d], hi = HiT[j*64+d];
                float wr = Wo_re[(size_t)(h*64+j)*512 + c];
                float wi = Wo_im[(size_t)(h*64+j)*512 + c];
                s += hr*wi + hi*wr;
            }
            if (p == 0) s = -s;
        }
        Wbig[(size_t)np*1024 + kk] = f2b(s);
    }
}

// ---------------- 5. GEMM: C = A @ Bt^T, MT x 128 tile, BK=64, XOR-swizzled LDS tiles.
// MODE 0: QKV gemm (+fused V^T gemm); MODE 1: out gemm, A = weighted merge of 2 bf16 partials.
template<int MODE, int MT>
__global__ __launch_bounds__(256, 2) void k_gemm(
        const unsigned short* __restrict__ Ain, const unsigned short* __restrict__ Btin,
        void* __restrict__ Cout, unsigned short* __restrict__ Vt,
        const float* __restrict__ Lp, int K) {
    __shared__ __align__(16) unsigned short Al[2][MT*32];
    __shared__ __align__(16) unsigned short Bl[2][128*32];
    const int t = threadIdx.x;
    const int wave = t >> 6, lane = t & 63, quad = lane >> 4, l16 = lane & 15;
    const int wr = wave >> 1, wc = wave & 1;
    const int quadx = quad ^ ((l16 >> 2) & 3);   // read-side un-swizzle (per-lane constant)

    const unsigned short* A;
    const unsigned short* Bt;
    unsigned short* Cb = nullptr;
    int m0, n0;
    if (MODE == 0) {
        if (blockIdx.y < 16) {
            A = Ain; Bt = Btin;
            m0 = blockIdx.x * 128; n0 = blockIdx.y * 128;
            Cb = (unsigned short*)Cout;
        } else {
            int idx = (blockIdx.y - 16) * 32 + blockIdx.x;
            int b = idx >> 7, mt = (idx >> 4) & 7, nt = idx & 15;
            A  = Btin + 2048*512;
            Bt = Ain + (size_t)b*2048*512;
            m0 = mt * 128; n0 = nt * 128;
            Cb = Vt + (size_t)b*1024*2048;
        }
    } else {
        A = Ain; Bt = Btin;
        m0 = blockIdx.x * MT; n0 = blockIdx.y * 128;
    }

    f32x4 acc[MT/32][4] = {};
    for (int kt = 0; kt < K; kt += 64) {
        if (MODE == 1) {
            // A-staging with fused split-K merge (swizzled slot <- swizzled global chunk)
            int r = t >> 2;
            int grs = (t & 3) ^ ((t >> 4) & 3);
            int row = m0 + r;
            #pragma unroll
            for (int kh = 0; kh < 2; kh++) {
                int kk = kt + kh*32 + grs*8;
                int hh = kk >> 7;
                float l0 = Lp[(size_t)row*8 + hh];
                float l1 = Lp[32768 + (size_t)row*8 + hh];
                float invl = 1.0f / (l0 + l1);
                float w0 = l0*invl, w1 = l1*invl;
                size_t off = (size_t)row*1024 + kk;
                bf16x8 a0 = *(const bf16x8*)&Ain[off];
                bf16x8 a1 = *(const bf16x8*)&Ain[4194304 + off];
                uint4 u;
                u.x = cvtpk(w0*b2f(a0[0]) + w1*b2f(a1[0]), w0*b2f(a0[1]) + w1*b2f(a1[1]));
                u.y = cvtpk(w0*b2f(a0[2]) + w1*b2f(a1[2]), w0*b2f(a0[3]) + w1*b2f(a1[3]));
                u.z = cvtpk(w0*b2f(a0[4]) + w1*b2f(a1[4]), w0*b2f(a0[5]) + w1*b2f(a1[5]));
                u.w = cvtpk(w0*b2f(a0[6]) + w1*b2f(a1[6]), w0*b2f(a0[7]) + w1*b2f(a1[7]));
                *(uint4*)&Al[kh][t*8] = u;
            }
        } else {
            #pragma unroll
            for (int kh = 0; kh < 2; kh++)
                #pragma unroll
                for (int i = 0; i < MT/64; i++) {
                    int g = t + i*256, r = g >> 2;
                    int grs = (g & 3) ^ ((g >> 4) & 3);
                    ld16(&Al[kh][g*8], &A[(size_t)(m0 + r)*K + kt + kh*32 + grs*8]);
                }
        }
        #pragma unroll
        for (int kh = 0; kh < 2; kh++)
            #pragma unroll
            for (int i = 0; i < 2; i++) {
                int g = t + i*256, r = g >> 2;
                int grs = (g & 3) ^ ((g >> 4) & 3);
                ld16(&Bl[kh][g*8], &Bt[(size_t)(n0 + r)*K + kt + kh*32 + grs*8]);
            }
        __syncthreads();
        #pragma unroll
        for (int kh = 0; kh < 2; kh++) {
            bf16x8 af[MT/32], bfr[4];
            #pragma unroll
            for (int rt = 0; rt < MT/32; rt++)
                af[rt] = *(const bf16x8*)&Al[kh][(wr*(MT/2) + rt*16 + l16)*32 + quadx*8];
            #pragma unroll
            for (int ct = 0; ct < 4; ct++)
                bfr[ct] = *(const bf16x8*)&Bl[kh][(wc*64 + ct*16 + l16)*32 + quadx*8];
            #pragma unroll
            for (int rt = 0; rt < MT/32; rt++)
                #pragma unroll
                for (int ct = 0; ct < 4; ct++)
                    acc[rt][ct] = __builtin_amdgcn_mfma_f32_16x16x32_bf16(af[rt], bfr[ct], acc[rt][ct], 0, 0, 0);
        }
        __syncthreads();
    }
    #pragma unroll
    for (int rt = 0; rt < MT/32; rt++) {
        int row = m0 + wr*(MT/2) + rt*16 + quad*4;
        #pragma unroll
        for (int ct = 0; ct < 4; ct++) {
            int col = n0 + wc*64 + ct*16 + l16;
            if (MODE == 0) {
                unsigned int u01 = cvtpk(acc[rt][ct][0], acc[rt][ct][1]);
                unsigned int u23 = cvtpk(acc[rt][ct][2], acc[rt][ct][3]);
                Cb[(size_t)(row+0)*2048 + col] = (unsigned short)(u01);
                Cb[(size_t)(row+1)*2048 + col] = (unsigned short)(u01 >> 16);
                Cb[(size_t)(row+2)*2048 + col] = (unsigned short)(u23);
                Cb[(size_t)(row+3)*2048 + col] = (unsigned short)(u23 >> 16);
            } else {
                float* C = (float*)Cout;
                #pragma unroll
                for (int r = 0; r < 4; r++)
                    C[(size_t)(row + r)*1024 + col] = acc[rt][ct][r];
            }
        }
    }
}

// ---------------- 6. flash attention: split-2 across blocks, KT=64, K+V LDS dbuf (swizzled), 1 barrier/iter.
// Block = (bh, qb, half): 4 waves x 32 q = 128 q; keys half*1024..+1023, 16 iters.
// Partials: per-half normalized O (bf16) + l (f32); merge fused into out-GEMM A-staging.
__global__ __launch_bounds__(256, 2) void k_attn(
        const unsigned short* __restrict__ QK,   // [4096][2048]
        const unsigned short* __restrict__ Vt,   // [2048][2048]
        unsigned short* __restrict__ Opart,      // [2][4096][1024] bf16 (normalized per half)
        float* __restrict__ Lpart) {             // [2][4096][8]
    __shared__ __align__(16) unsigned short Kl[2][8192];  // [buf][4ks][64key][32d]  32KB (swizzled)
    __shared__ __align__(16) unsigned short Vl[2][8192];  // [buf][2ks2][128d][32key] 32KB (swizzled)
    __shared__ __align__(16) unsigned short Pl[4608];     // [128q][36]               9KB

    const int t = threadIdx.x, w = t >> 6, lane = t & 63, quad = lane >> 4, l16 = lane & 15;
    const int quadx = quad ^ ((l16 >> 2) & 3);   // read-side un-swizzle
    const int bh = blockIdx.x, b = bh >> 3, h = bh & 7;
    const int qb = blockIdx.y & 15, half = blockIdx.y >> 4;
    const int tok0 = b*2048 + qb*128;

    // Q fragments straight from global (read once)
    bf16x8 qf[2][4];
    #pragma unroll
    for (int rt = 0; rt < 2; rt++)
        #pragma unroll
        for (int ks = 0; ks < 4; ks++)
            qf[rt][ks] = *(const bf16x8*)&QK[(size_t)(tok0 + w*32 + rt*16 + l16)*2048 + h*128 + ks*32 + quad*8];

    // staging pointers with swizzled chunk: grs = (t&3) ^ ((t>>4)&3); row = t>>2
    const int grs = (t & 3) ^ ((t >> 4) & 3);
    const unsigned short* kp = QK + (size_t)(b*2048 + half*1024 + (t >> 2))*2048 + 1024 + h*128 + grs*8;
    const unsigned short* vp = Vt + (size_t)(b*1024 + h*128 + (t >> 2))*2048 + half*1024 + grs*8;

    f32x4 Oacc[2][8] = {};
    float ls[2][4] = {};

    // prologue: stage tile 0 into buf 0
    #pragma unroll
    for (int i = 0; i < 4; i++) ld16(&Kl[0][(i*256 + t)*8], kp + i*32);
    #pragma unroll
    for (int i = 0; i < 4; i++) ld16(&Vl[0][(i*256 + t)*8], vp + (i & 1)*131072 + (i >> 1)*32);
    __syncthreads();

    for (int it = 0; it < 16; it++) {
        const int cur = it & 1;
        if (it < 15) {   // async prefetch next K+V tiles (only vmcnt consumers -> drain at barrier, hidden)
            int kt2 = (it + 1) * 64;
            #pragma unroll
            for (int i = 0; i < 4; i++) ld16(&Kl[cur^1][(i*256 + t)*8], kp + (size_t)kt2*2048 + i*32);
            #pragma unroll
            for (int i = 0; i < 4; i++) ld16(&Vl[cur^1][(i*256 + t)*8], vp + kt2 + (i & 1)*131072 + (i >> 1)*32);
        }

        // S = Q~ @ K^T : 32 q x 64 keys per wave
        f32x4 S[2][4] = {};
        #pragma unroll
        for (int ks = 0; ks < 4; ks++) {
            #pragma unroll
            for (int ct = 0; ct < 4; ct++) {
                bf16x8 kf = *(const bf16x8*)&Kl[cur][ks*2048 + (ct*16 + l16)*32 + quadx*8];
                #pragma unroll
                for (int rt = 0; rt < 2; rt++)
                    S[rt][ct] = __builtin_amdgcn_mfma_f32_16x16x32_bf16(qf[rt][ks], kf, S[rt][ct], 0, 0, 0);
            }
        }
        // per-ks2: exp -> P(LDS, wave-private, reused region) -> PV
        #pragma unroll
        for (int ks2 = 0; ks2 < 2; ks2++) {
            #pragma unroll
            for (int rt = 0; rt < 2; rt++) {
                #pragma unroll
                for (int ct2 = 0; ct2 < 2; ct2++) {
                    int ct = ks2*2 + ct2;
                    float p0 = exp2f(S[rt][ct][0]), p1 = exp2f(S[rt][ct][1]);
                    float p2 = exp2f(S[rt][ct][2]), p3 = exp2f(S[rt][ct][3]);
                    ls[rt][0] += p0; ls[rt][1] += p1; ls[rt][2] += p2; ls[rt][3] += p3;
                    int q = w*32 + rt*16 + quad*4;
                    int base = ct2*16 + l16;
                    unsigned int u01 = cvtpk(p0, p1);
                    unsigned int u23 = cvtpk(p2, p3);
                    Pl[base + (q+0)*36] = (unsigned short)(u01);
                    Pl[base + (q+1)*36] = (unsigned short)(u01 >> 16);
                    Pl[base + (q+2)*36] = (unsigned short)(u23);
                    Pl[base + (q+3)*36] = (unsigned short)(u23 >> 16);
                }
            }
            bf16x8 pf[2];
            #pragma unroll
            for (int rt = 0; rt < 2; rt++)
                pf[rt] = *(const bf16x8*)&Pl[(w*32 + rt*16 + l16)*36 + quad*8];
            #pragma unroll
            for (int dt = 0; dt < 8; dt++) {
                bf16x8 vf = *(const bf16x8*)&Vl[cur][ks2*4096 + (dt*16 + l16)*32 + quadx*8];
                #pragma unroll
                for (int rt = 0; rt < 2; rt++)
                    Oacc[rt][dt] = __builtin_amdgcn_mfma_f32_16x16x32_bf16(pf[rt], vf, Oacc[rt][dt], 0, 0, 0);
            }
        }
        __syncthreads();   // cur bufs free; prefetched bufs complete
    }

    // reduce denominators across 16 key-col lanes; normalize partial, store bf16 + l
    #pragma unroll
    for (int rt = 0; rt < 2; rt++)
        #pragma unroll
        for (int r = 0; r < 4; r++) {
            float s = ls[rt][r];
            #pragma unroll
            for (int m = 1; m < 16; m <<= 1) s += __shfl_xor(s, m, 64);
            ls[rt][r] = s;
        }
    unsigned short* Op = Opart + (size_t)half*4096*1024;
    float* Lp = Lpart + (size_t)half*32768;
    #pragma unroll
    for (int rt = 0; rt < 2; rt++) {
        int q = w*32 + rt*16 + quad*4;
        int tok = tok0 + q;
        float inv[4];
        #pragma unroll
        for (int r = 0; r < 4; r++) inv[r] = 1.0f / ls[rt][r];
        if (l16 == 0) {
            #pragma unroll
            for (int r = 0; r < 4; r++) Lp[(size_t)(tok + r)*8 + h] = ls[rt][r];
        }
        #pragma unroll
        for (int dt = 0; dt < 8; dt++) {
            int col = h*128 + dt*16 + l16;
            #pragma unroll
            for (int r = 0; r < 4; r++)
                Op[(size_t)(tok + r)*1024 + col] = f2b(Oacc[rt][dt][r] * inv[r]);
        }
    }
}

extern "C" void kernel_launch(void* const* d_in, const int* in_sizes, int n_in,
                              void* d_out, int out_size, void* d_ws, size_t ws_size,
                              hipStream_t stream) {
    (void)in_sizes; (void)n_in; (void)out_size; (void)ws_size;
    const float* x      = (const float*)d_in[0];
    const float* Wq_re  = (const float*)d_in[1];
    const float* Wq_im  = (const float*)d_in[2];
    const float* Wk_re  = (const float*)d_in[3];
    const float* Wk_im  = (const float*)d_in[4];
    const float* Wv_re  = (const float*)d_in[5];
    const float* Wv_im  = (const float*)d_in[6];
    const float* Wm_re  = (const float*)d_in[7];
    const float* Wm_im  = (const float*)d_in[8];
    const float* Wmi_re = (const float*)d_in[9];
    const float* Wmi_im = (const float*)d_in[10];
    const float* Wo_re  = (const float*)d_in[11];
    const float* Wo_im  = (const float*)d_in[12];

    char* ws = (char*)d_ws;
    unsigned short* xn    = (unsigned short*)(ws);
    unsigned short* WqkvT = (unsigned short*)(ws + (4u << 20));
    unsigned short* Wbig  = (unsigned short*)(ws + (7u << 20));
    float*          GH    = (float*)         (ws + (9u << 20));
    float*          WmT_re= (float*)         (ws + (9u << 20) + (64u << 10));
    float*          WmT_im= (float*)         (ws + (9u << 20) + (128u << 10));
    unsigned short* QK    = (unsigned short*)(ws + (10u << 20));
    unsigned short* Vt    = (unsigned short*)(ws + (26u << 20));
    unsigned short* Opart = (unsigned short*)(ws + (42u << 20));
    float*          Lpart = (float*)         (ws + (74u << 20));
    // transient fp32 transposes inside QK's region (overwritten by gemm0 later)
    float* WqT_re = (float*)(ws + (10u << 20));
    float* WqT_im = (float*)(ws + (11u << 20));
    float* WkT_re = (float*)(ws + (12u << 20));
    float* WkT_im = (float*)(ws + (13u << 20));
    float* WvT_re = (float*)(ws + (14u << 20));
    float* WvT_im = (float*)(ws + (15u << 20));

    k_prep      <<<dim3(1416), dim3(256), 0, stream>>>(
        x, xn,
        Wq_re, Wq_im, Wk_re, Wk_im, Wv_re, Wv_im, Wm_re, Wm_im,
        WqT_re, WqT_im, WkT_re, WkT_im, WvT_re, WvT_im, WmT_re, WmT_im);
    k_gh        <<<dim3(64),   dim3(256), 0, stream>>>(Wm_re, Wm_im, WmT_re, WmT_im, Wmi_re, Wmi_im, GH);
    k_pack      <<<dim3(10240),dim3(256), 0, stream>>>(
        WqT_re, WqT_im, WkT_re, WkT_im, WvT_re, WvT_im, Wo_re, Wo_im, GH, WqkvT, Wbig);
    k_gemm<0,128><<<dim3(32, 24), dim3(256), 0, stream>>>(xn, WqkvT, (void*)QK, Vt, nullptr, 512);
    k_attn      <<<dim3(16, 32), dim3(256), 0, stream>>>(QK, Vt, Opart, Lpart);
    k_gemm<1,64> <<<dim3(64, 8), dim3(256), 0, stream>>>(Opart, Wbig, d_out, nullptr, Lpart, 1024);
}

// Round 12
// 236.870 us; speedup vs baseline: 1.0557x; 1.0557x over previous
//
#include <hip/hip_runtime.h>
#include <hip/hip_bf16.h>
#include <stdint.h>

// QuantumGeometricAttention — algebraic refactor:
//   G = Wm Wm^H folded into Wq (scores inner dim 128 real)  — fold done as MFMA GEMM (MODE 2)
//   H = Wm Wmi  folded into Wo (PV inner dim 128 real)
// prep(norm + K/V transpose->bf16 + Wm transpose + Bq reshape) -> gh(G,Ht + Aq matrix)
//   -> qfold GEMM -> packwo -> [QKV GEMM + V^T GEMM] -> flash attn (split-2, bf16 partials)
//   -> out GEMM (fused split-K merge).
// ws: 0 xn | 4MB WqkvT | 7MB Wbig | 9MB GH | +64K WmT_re | +128K WmT_im | +192K Aq bf16[128][128]
//     10MB QK bf16[4096][2048] (Bq bf16[4096][128] transiently at 10MB, consumed before gemm0 writes QK)
//     26MB Vt bf16[2048][2048] | 42MB Opart bf16[2][4096][1024] | 74MB Lpart f32[2][4096][8]

typedef __attribute__((ext_vector_type(8))) short bf16x8;
typedef __attribute__((ext_vector_type(4))) float f32x4;

#define QSCALE 0.18033688011112042f  /* 64^-0.5 * log2(e) */

__device__ __forceinline__ unsigned short f2b(float f) {
    union { float f; unsigned int u; } v; v.f = f;
    unsigned int r = v.u + 0x7fffu + ((v.u >> 16) & 1u);
    return (unsigned short)(r >> 16);
}

__device__ __forceinline__ float b2f(short s) {
    union { float f; unsigned int u; } v;
    v.u = ((unsigned int)(unsigned short)s) << 16;
    return v.f;
}

__device__ __forceinline__ unsigned int cvtpk(float a, float b) {
    union { __hip_bfloat162 h; unsigned int u; } v;
    v.h = __float22bfloat162_rn(make_float2(a, b));
    return v.u;
}

__device__ __forceinline__ void ld16(void* lds, const void* g) {
    __builtin_amdgcn_global_load_lds(
        (__attribute__((address_space(1))) unsigned int*)(g),
        (__attribute__((address_space(3))) unsigned int*)(lds), 16, 0, 0);
}

// ---------------- 1. prep ----------------
// blocks 0..1023   : row L2-norm of x -> xn bf16
// blocks 1024..1279: Wk/Wv 512x512 transposes -> bf16 directly into WqkvT K/V sections
// blocks 1280..1287: Wm transposes -> WmT fp32
// blocks 1288..1415: Bq reshape: Bq[h*512+k][reim*64+d] = Wq_reim[k][h*64+d] (bf16, coalesced copy)
__global__ __launch_bounds__(256) void k_prep(
        const float* __restrict__ x, unsigned short* __restrict__ xn,
        const float* __restrict__ Wq_re, const float* __restrict__ Wq_im,
        const float* __restrict__ Wk_re, const float* __restrict__ Wk_im,
        const float* __restrict__ Wv_re, const float* __restrict__ Wv_im,
        const float* __restrict__ Wm_re, const float* __restrict__ Wm_im,
        unsigned short* __restrict__ WqkvT, unsigned short* __restrict__ Bq,
        float* __restrict__ WmT_re, float* __restrict__ WmT_im) {
    __shared__ float tile[64][65];
    if (blockIdx.x < 1024) {
        int row  = blockIdx.x * 4 + (threadIdx.x >> 6);
        int lane = threadIdx.x & 63;
        const float4* xr = (const float4*)(x + (size_t)row * 512);
        float4 a = xr[lane], b = xr[lane + 64];
        float s = a.x*a.x + a.y*a.y + a.z*a.z + a.w*a.w
                + b.x*b.x + b.y*b.y + b.z*b.z + b.w*b.w;
        #pragma unroll
        for (int m = 1; m < 64; m <<= 1) s += __shfl_xor(s, m, 64);
        float inv = 1.0f / sqrtf(s);
        ushort4 o;
        o.x = f2b(a.x*inv); o.y = f2b(a.y*inv); o.z = f2b(a.z*inv); o.w = f2b(a.w*inv);
        *(ushort4*)&xn[(size_t)row*512 + lane*4] = o;
        o.x = f2b(b.x*inv); o.y = f2b(b.y*inv); o.z = f2b(b.z*inv); o.w = f2b(b.w*inv);
        *(ushort4*)&xn[(size_t)row*512 + 256 + lane*4] = o;
        return;
    }
    int bid = blockIdx.x - 1024;
    int tx = threadIdx.x & 63, ty = threadIdx.x >> 6;
    if (bid < 256) {
        // K/V transposes -> bf16 into WqkvT
        int mat = bid >> 6, tl = bid & 63;   // 0=Wk_re,1=Wk_im,2=Wv_re,3=Wv_im
        const float* src = (mat==0)?Wk_re:(mat==1)?Wk_im:(mat==2)?Wv_re:Wv_im;
        int r0 = (tl >> 3) * 64, c0 = (tl & 7) * 64;
        #pragma unroll
        for (int i = 0; i < 16; i++) {
            int r = ty + i*4;
            tile[r][tx] = src[(size_t)(r0 + r)*512 + c0 + tx];
        }
        __syncthreads();
        int sec = 1024 + (mat >> 1)*1024, part = mat & 1;
        #pragma unroll
        for (int i = 0; i < 16; i++) {
            int r = ty + i*4;
            int rr = c0 + r, h = rr >> 6, j = rr & 63;
            WqkvT[(size_t)(sec + h*128 + part*64 + j)*512 + r0 + tx] = f2b(tile[tx][r]);
        }
    } else if (bid < 264) {
        // Wm transposes -> fp32 WmT [256][64]
        int mat = (bid - 256) >> 2, tl = (bid - 256) & 3;
        const float* src = mat ? Wm_im : Wm_re;
        float* dst = mat ? WmT_im : WmT_re;
        int c0 = tl * 64;
        #pragma unroll
        for (int i = 0; i < 16; i++) {
            int r = ty + i*4;
            tile[r][tx] = src[(size_t)r*256 + c0 + tx];
        }
        __syncthreads();
        #pragma unroll
        for (int i = 0; i < 16; i++) {
            int r = ty + i*4;
            dst[(size_t)(c0 + r)*64 + tx] = tile[tx][r];
        }
    } else {
        // Bq reshape (coalesced read + coalesced write)
        int b3 = bid - 264;                  // 0..127
        int mat = b3 >> 6, tl = b3 & 63;
        const float* src = mat ? Wq_im : Wq_re;
        #pragma unroll
        for (int i = 0; i < 16; i++) {
            int idx = tl*4096 + i*256 + threadIdx.x;
            int k = idx >> 9, col = idx & 511;
            int h = col >> 6, d = col & 63;
            Bq[(size_t)(h*512 + k)*128 + mat*64 + d] = f2b(src[(size_t)k*512 + col]);
        }
    }
}

// ---------------- 2. G = Wm Wm^H, Ht = (Wm Wmi)^T; also emit Aq bf16[128][128] fold matrix ----------------
// Aq[p*64+j][reim*64+d]: p0: (Gr[d][j], -Gi[d][j]) ; p1: (Gi[d][j], Gr[d][j]) — all x QSCALE.
__global__ __launch_bounds__(256) void k_gh(const float* __restrict__ Wm_re, const float* __restrict__ Wm_im,
                                            const float* __restrict__ WmT_re, const float* __restrict__ WmT_im,
                                            const float* __restrict__ Wmi_re, const float* __restrict__ Wmi_im,
                                            float* __restrict__ GH, unsigned short* __restrict__ Aq) {
    int id = blockIdx.x * 256 + threadIdx.x;   // 16384
    int mat = id >> 12;
    int a = (id >> 6) & 63, c = id & 63;       // a wave-uniform, c = lane
    float s = 0.f;
    if (mat < 2) {
        for (int m = 0; m < 256; m++) {
            float ar = Wm_re[a*256+m], ai = Wm_im[a*256+m];   // broadcast
            float br = WmT_re[m*64+c], bi = WmT_im[m*64+c];   // lane-contiguous
            s += (mat == 0) ? (ar*br + ai*bi) : (ai*br - ar*bi);
        }
        float sq = s * QSCALE;
        if (mat == 0) {   // Gr[a][c] -> Aq[c][a], Aq[64+c][64+a]
            Aq[c*128 + a]           = f2b(sq);
            Aq[(64+c)*128 + 64 + a] = f2b(sq);
        } else {          // Gi[a][c] -> Aq[64+c][a], -Gi -> Aq[c][64+a]
            Aq[(64+c)*128 + a]      = f2b(sq);
            Aq[c*128 + 64 + a]      = f2b(-sq);
        }
    } else {
        for (int m = 0; m < 256; m++) {
            float ar = Wm_re[a*256+m], ai = Wm_im[a*256+m];
            float br = Wmi_re[m*64+c], bi = Wmi_im[m*64+c];
            s += (mat == 2) ? (ar*br - ai*bi) : (ar*bi + ai*br);
        }
        GH[mat*4096 + c*64 + a] = s;   // store H transposed
    }
}

// ---------------- 3. Wo fold: Wbig [1024][1024] bf16 ----------------
__global__ __launch_bounds__(256) void k_packwo(
        const float* __restrict__ Wo_re,  const float* __restrict__ Wo_im,
        const float* __restrict__ GH, unsigned short* __restrict__ Wbig) {
    int id = blockIdx.x * 256 + threadIdx.x;
    int np = id >> 10, kk = id & 1023;         // np wave-uniform, lanes vary d
    int c = np >> 1, p = np & 1;
    int h = kk >> 7, pp = (kk >> 6) & 1, d = kk & 63;
    const float* HrT = GH + 2*4096;
    const float* HiT = GH + 3*4096;
    float s = 0.f;
    if (p == pp) {
        for (int j = 0; j < 64; j++) {
            float hr = HrT[j*64+d], hi = HiT[j*64+d];
            float wr = Wo_re[(size_t)(h*64+j)*512 + c];
            float wi = Wo_im[(size_t)(h*64+j)*512 + c];
            s += hr*wr - hi*wi;
        }
    } else {
        for (int j = 0; j < 64; j++) {
            float hr = HrT[j*64+d], hi = HiT[j*64+d];
            float wr = Wo_re[(size_t)(h*64+j)*512 + c];
            float wi = Wo_im[(size_t)(h*64+j)*512 + c];
            s += hr*wi + hi*wr;
        }
        if (p == 0) s = -s;
    }
    Wbig[(size_t)np*1024 + kk] = f2b(s);
}

// ---------------- 5. GEMM: C = A @ Bt^T, MT x 128 tile, BK=64.
// MODE 0: QKV gemm (+fused V^T gemm). MODE 1: out gemm, A = weighted merge of 2 bf16 partials.
// MODE 2: Q-fold gemm: C[128][4096] = Aq @ Bq^T -> WqkvT Q-section (row n'=part*64+j, col=h*512+k).
template<int MODE, int MT>
__global__ __launch_bounds__(256, 2) void k_gemm(
        const unsigned short* __restrict__ Ain, const unsigned short* __restrict__ Btin,
        void* __restrict__ Cout, unsigned short* __restrict__ Vt,
        const float* __restrict__ Lp, int K) {
    __shared__ __align__(16) unsigned short Al[2][MT*32];
    __shared__ __align__(16) unsigned short Bl[2][128*32];
    const int t = threadIdx.x;
    const int wave = t >> 6, lane = t & 63, quad = lane >> 4, l16 = lane & 15;
    const int wr = wave >> 1, wc = wave & 1;

    const unsigned short* A;
    const unsigned short* Bt;
    unsigned short* Cb = nullptr;
    int m0, n0;
    if (MODE == 0) {
        if (blockIdx.y < 16) {
            A = Ain; Bt = Btin;
            m0 = blockIdx.x * 128; n0 = blockIdx.y * 128;
            Cb = (unsigned short*)Cout;
        } else {
            int idx = (blockIdx.y - 16) * 32 + blockIdx.x;
            int b = idx >> 7, mt = (idx >> 4) & 7, nt = idx & 15;
            A  = Btin + 2048*512;
            Bt = Ain + (size_t)b*2048*512;
            m0 = mt * 128; n0 = nt * 128;
            Cb = Vt + (size_t)b*1024*2048;
        }
    } else {
        A = Ain; Bt = Btin;
        m0 = blockIdx.x * MT; n0 = blockIdx.y * 128;
    }

    f32x4 acc[MT/32][4] = {};
    for (int kt = 0; kt < K; kt += 64) {
        if (MODE == 1) {
            // A-staging with fused split-K merge: Ain = Opart bf16 [2][4096][1024]
            int r = t >> 2, gr = t & 3;
            int row = m0 + r;
            #pragma unroll
            for (int kh = 0; kh < 2; kh++) {
                int kk = kt + kh*32 + gr*8;
                int hh = kk >> 7;
                float l0 = Lp[(size_t)row*8 + hh];
                float l1 = Lp[32768 + (size_t)row*8 + hh];
                float invl = 1.0f / (l0 + l1);
                float w0 = l0*invl, w1 = l1*invl;
                size_t off = (size_t)row*1024 + kk;
                bf16x8 a0 = *(const bf16x8*)&Ain[off];
                bf16x8 a1 = *(const bf16x8*)&Ain[4194304 + off];
                uint4 u;
                u.x = cvtpk(w0*b2f(a0[0]) + w1*b2f(a1[0]), w0*b2f(a0[1]) + w1*b2f(a1[1]));
                u.y = cvtpk(w0*b2f(a0[2]) + w1*b2f(a1[2]), w0*b2f(a0[3]) + w1*b2f(a1[3]));
                u.z = cvtpk(w0*b2f(a0[4]) + w1*b2f(a1[4]), w0*b2f(a0[5]) + w1*b2f(a1[5]));
                u.w = cvtpk(w0*b2f(a0[6]) + w1*b2f(a1[6]), w0*b2f(a0[7]) + w1*b2f(a1[7]));
                *(uint4*)&Al[kh][t*8] = u;
            }
        } else {
            #pragma unroll
            for (int kh = 0; kh < 2; kh++)
                #pragma unroll
                for (int i = 0; i < MT/64; i++) {
                    int g = t + i*256, r = g >> 2, gr = g & 3;
                    ld16(&Al[kh][g*8], &A[(size_t)(m0 + r)*K + kt + kh*32 + gr*8]);
                }
        }
        #pragma unroll
        for (int kh = 0; kh < 2; kh++)
            #pragma unroll
            for (int i = 0; i < 2; i++) {
                int g = t + i*256, r = g >> 2, gr = g & 3;
                ld16(&Bl[kh][g*8], &Bt[(size_t)(n0 + r)*K + kt + kh*32 + gr*8]);
            }
        __syncthreads();
        #pragma unroll
        for (int kh = 0; kh < 2; kh++) {
            bf16x8 af[MT/32], bfr[4];
            #pragma unroll
            for (int rt = 0; rt < MT/32; rt++)
                af[rt] = *(const bf16x8*)&Al[kh][(wr*(MT/2) + rt*16 + l16)*32 + quad*8];
            #pragma unroll
            for (int ct = 0; ct < 4; ct++)
                bfr[ct] = *(const bf16x8*)&Bl[kh][(wc*64 + ct*16 + l16)*32 + quad*8];
            #pragma unroll
            for (int rt = 0; rt < MT/32; rt++)
                #pragma unroll
                for (int ct = 0; ct < 4; ct++)
                    acc[rt][ct] = __builtin_amdgcn_mfma_f32_16x16x32_bf16(af[rt], bfr[ct], acc[rt][ct], 0, 0, 0);
        }
        __syncthreads();
    }
    #pragma unroll
    for (int rt = 0; rt < MT/32; rt++) {
        int row = m0 + wr*(MT/2) + rt*16 + quad*4;
        #pragma unroll
        for (int ct = 0; ct < 4; ct++) {
            int col = n0 + wc*64 + ct*16 + l16;
            if (MODE == 0) {
                unsigned int u01 = cvtpk(acc[rt][ct][0], acc[rt][ct][1]);
                unsigned int u23 = cvtpk(acc[rt][ct][2], acc[rt][ct][3]);
                Cb[(size_t)(row+0)*2048 + col] = (unsigned short)(u01);
                Cb[(size_t)(row+1)*2048 + col] = (unsigned short)(u01 >> 16);
                Cb[(size_t)(row+2)*2048 + col] = (unsigned short)(u23);
                Cb[(size_t)(row+3)*2048 + col] = (unsigned short)(u23 >> 16);
            } else if (MODE == 2) {
                unsigned short* Cq = (unsigned short*)Cout;
                int h = col >> 9, k = col & 511;
                unsigned int u01 = cvtpk(acc[rt][ct][0], acc[rt][ct][1]);
                unsigned int u23 = cvtpk(acc[rt][ct][2], acc[rt][ct][3]);
                Cq[(size_t)(h*128 + row + 0)*512 + k] = (unsigned short)(u01);
                Cq[(size_t)(h*128 + row + 1)*512 + k] = (unsigned short)(u01 >> 16);
                Cq[(size_t)(h*128 + row + 2)*512 + k] = (unsigned short)(u23);
                Cq[(size_t)(h*128 + row + 3)*512 + k] = (unsigned short)(u23 >> 16);
            } else {
                float* C = (float*)Cout;
                #pragma unroll
                for (int r = 0; r < 4; r++)
                    C[(size_t)(row + r)*1024 + col] = acc[rt][ct][r];
            }
        }
    }
}

// ---------------- 6. flash attention: split-2 across blocks, KT=64, K+V LDS dbuf, 1 barrier/iter.
__global__ __launch_bounds__(256, 2) void k_attn(
        const unsigned short* __restrict__ QK,   // [4096][2048]
        const unsigned short* __restrict__ Vt,   // [2048][2048]
        unsigned short* __restrict__ Opart,      // [2][4096][1024] bf16 (normalized per half)
        float* __restrict__ Lpart) {             // [2][4096][8]
    __shared__ __align__(16) unsigned short Kl[2][8192];  // [buf][4ks][64key][32d]  32KB (swizzled)
    __shared__ __align__(16) unsigned short Vl[2][8192];  // [buf][2ks2][128d][32key] 32KB (swizzled)
    __shared__ __align__(16) unsigned short Pl[4608];     // [128q][36]               9KB

    const int t = threadIdx.x, w = t >> 6, lane = t & 63, quad = lane >> 4, l16 = lane & 15;
    const int quadx = quad ^ ((l16 >> 2) & 3);   // read-side un-swizzle
    const int bh = blockIdx.x, b = bh >> 3, h = bh & 7;
    const int qb = blockIdx.y & 15, half = blockIdx.y >> 4;
    const int tok0 = b*2048 + qb*128;

    bf16x8 qf[2][4];
    #pragma unroll
    for (int rt = 0; rt < 2; rt++)
        #pragma unroll
        for (int ks = 0; ks < 4; ks++)
            qf[rt][ks] = *(const bf16x8*)&QK[(size_t)(tok0 + w*32 + rt*16 + l16)*2048 + h*128 + ks*32 + quad*8];

    const int grs = (t & 3) ^ ((t >> 4) & 3);
    const unsigned short* kp = QK + (size_t)(b*2048 + half*1024 + (t >> 2))*2048 + 1024 + h*128 + grs*8;
    const unsigned short* vp = Vt + (size_t)(b*1024 + h*128 + (t >> 2))*2048 + half*1024 + grs*8;

    f32x4 Oacc[2][8] = {};
    float ls[2][4] = {};

    #pragma unroll
    for (int i = 0; i < 4; i++) ld16(&Kl[0][(i*256 + t)*8], kp + i*32);
    #pragma unroll
    for (int i = 0; i < 4; i++) ld16(&Vl[0][(i*256 + t)*8], vp + (i & 1)*131072 + (i >> 1)*32);
    __syncthreads();

    for (int it = 0; it < 16; it++) {
        const int cur = it & 1;
        if (it < 15) {
            int kt2 = (it + 1) * 64;
            #pragma unroll
            for (int i = 0; i < 4; i++) ld16(&Kl[cur^1][(i*256 + t)*8], kp + (size_t)kt2*2048 + i*32);
            #pragma unroll
            for (int i = 0; i < 4; i++) ld16(&Vl[cur^1][(i*256 + t)*8], vp + kt2 + (i & 1)*131072 + (i >> 1)*32);
        }

        f32x4 S[2][4] = {};
        #pragma unroll
        for (int ks = 0; ks < 4; ks++) {
            #pragma unroll
            for (int ct = 0; ct < 4; ct++) {
                bf16x8 kf = *(const bf16x8*)&Kl[cur][ks*2048 + (ct*16 + l16)*32 + quadx*8];
                #pragma unroll
                for (int rt = 0; rt < 2; rt++)
                    S[rt][ct] = __builtin_amdgcn_mfma_f32_16x16x32_bf16(qf[rt][ks], kf, S[rt][ct], 0, 0, 0);
            }
        }
        #pragma unroll
        for (int ks2 = 0; ks2 < 2; ks2++) {
            #pragma unroll
            for (int rt = 0; rt < 2; rt++) {
                #pragma unroll
                for (int ct2 = 0; ct2 < 2; ct2++) {
                    int ct = ks2*2 + ct2;
                    float p0 = exp2f(S[rt][ct][0]), p1 = exp2f(S[rt][ct][1]);
                    float p2 = exp2f(S[rt][ct][2]), p3 = exp2f(S[rt][ct][3]);
                    ls[rt][0] += p0; ls[rt][1] += p1; ls[rt][2] += p2; ls[rt][3] += p3;
                    int q = w*32 + rt*16 + quad*4;
                    int base = ct2*16 + l16;
                    unsigned int u01 = cvtpk(p0, p1);
                    unsigned int u23 = cvtpk(p2, p3);
                    Pl[base + (q+0)*36] = (unsigned short)(u01);
                    Pl[base + (q+1)*36] = (unsigned short)(u01 >> 16);
                    Pl[base + (q+2)*36] = (unsigned short)(u23);
                    Pl[base + (q+3)*36] = (unsigned short)(u23 >> 16);
                }
            }
            bf16x8 pf[2];
            #pragma unroll
            for (int rt = 0; rt < 2; rt++)
                pf[rt] = *(const bf16x8*)&Pl[(w*32 + rt*16 + l16)*36 + quad*8];
            #pragma unroll
            for (int dt = 0; dt < 8; dt++) {
                bf16x8 vf = *(const bf16x8*)&Vl[cur][ks2*4096 + (dt*16 + l16)*32 + quadx*8];
                #pragma unroll
                for (int rt = 0; rt < 2; rt++)
                    Oacc[rt][dt] = __builtin_amdgcn_mfma_f32_16x16x32_bf16(pf[rt], vf, Oacc[rt][dt], 0, 0, 0);
            }
        }
        __syncthreads();
    }

    #pragma unroll
    for (int rt = 0; rt < 2; rt++)
        #pragma unroll
        for (int r = 0; r < 4; r++) {
            float s = ls[rt][r];
            #pragma unroll
            for (int m = 1; m < 16; m <<= 1) s += __shfl_xor(s, m, 64);
            ls[rt][r] = s;
        }
    unsigned short* Op = Opart + (size_t)half*4096*1024;
    float* Lp = Lpart + (size_t)half*32768;
    #pragma unroll
    for (int rt = 0; rt < 2; rt++) {
        int q = w*32 + rt*16 + quad*4;
        int tok = tok0 + q;
        float inv[4];
        #pragma unroll
        for (int r = 0; r < 4; r++) inv[r] = 1.0f / ls[rt][r];
        if (l16 == 0) {
            #pragma unroll
            for (int r = 0; r < 4; r++) Lp[(size_t)(tok + r)*8 + h] = ls[rt][r];
        }
        #pragma unroll
        for (int dt = 0; dt < 8; dt++) {
            int col = h*128 + dt*16 + l16;
            #pragma unroll
            for (int r = 0; r < 4; r++)
                Op[(size_t)(tok + r)*1024 + col] = f2b(Oacc[rt][dt][r] * inv[r]);
        }
    }
}

extern "C" void kernel_launch(void* const* d_in, const int* in_sizes, int n_in,
                              void* d_out, int out_size, void* d_ws, size_t ws_size,
                              hipStream_t stream) {
    (void)in_sizes; (void)n_in; (void)out_size; (void)ws_size;
    const float* x      = (const float*)d_in[0];
    const float* Wq_re  = (const float*)d_in[1];
    const float* Wq_im  = (const float*)d_in[2];
    const float* Wk_re  = (const float*)d_in[3];
    const float* Wk_im  = (const float*)d_in[4];
    const float* Wv_re  = (const float*)d_in[5];
    const float* Wv_im  = (const float*)d_in[6];
    const float* Wm_re  = (const float*)d_in[7];
    const float* Wm_im  = (const float*)d_in[8];
    const float* Wmi_re = (const float*)d_in[9];
    const float* Wmi_im = (const float*)d_in[10];
    const float* Wo_re  = (const float*)d_in[11];
    const float* Wo_im  = (const float*)d_in[12];

    char* ws = (char*)d_ws;
    unsigned short* xn    = (unsigned short*)(ws);
    unsigned short* WqkvT = (unsigned short*)(ws + (4u << 20));
    unsigned short* Wbig  = (unsigned short*)(ws + (7u << 20));
    float*          GH    = (float*)         (ws + (9u << 20));
    float*          WmT_re= (float*)         (ws + (9u << 20) + (64u << 10));
    float*          WmT_im= (float*)         (ws + (9u << 20) + (128u << 10));
    unsigned short* Aq    = (unsigned short*)(ws + (9u << 20) + (192u << 10));
    unsigned short* QK    = (unsigned short*)(ws + (10u << 20));
    unsigned short* Bq    = (unsigned short*)(ws + (10u << 20));   // transient, consumed pre-gemm0
    unsigned short* Vt    = (unsigned short*)(ws + (26u << 20));
    unsigned short* Opart = (unsigned short*)(ws + (42u << 20));
    float*          Lpart = (float*)         (ws + (74u << 20));

    k_prep       <<<dim3(1416), dim3(256), 0, stream>>>(
        x, xn, Wq_re, Wq_im, Wk_re, Wk_im, Wv_re, Wv_im, Wm_re, Wm_im,
        WqkvT, Bq, WmT_re, WmT_im);
    k_gh         <<<dim3(64),   dim3(256), 0, stream>>>(
        Wm_re, Wm_im, WmT_re, WmT_im, Wmi_re, Wmi_im, GH, Aq);
    k_gemm<2,128><<<dim3(1, 32),  dim3(256), 0, stream>>>(Aq, Bq, (void*)WqkvT, nullptr, nullptr, 128);
    k_packwo     <<<dim3(4096), dim3(256), 0, stream>>>(Wo_re, Wo_im, GH, Wbig);
    k_gemm<0,128><<<dim3(32, 24), dim3(256), 0, stream>>>(xn, WqkvT, (void*)QK, Vt, nullptr, 512);
    k_attn       <<<dim3(16, 32), dim3(256), 0, stream>>>(QK, Vt, Opart, Lpart);
    k_gemm<1,64> <<<dim3(64, 8),  dim3(256), 0, stream>>>(Opart, Wbig, d_out, nullptr, Lpart, 1024);
}

// Round 13
// 233.456 us; speedup vs baseline: 1.0712x; 1.0146x over previous
//
#include <hip/hip_runtime.h>
#include <hip/hip_bf16.h>
#include <stdint.h>

// QuantumGeometricAttention — algebraic refactor:
//   G = Wm Wm^H folded into Wq (scores inner dim 128 real)  — fold done as MFMA GEMM (MODE 2)
//   H = Wm Wmi  folded into Wo (PV inner dim 128 real)
// prep -> gh -> qfold GEMM -> packwo -> [QKV GEMM + V^T GEMM] -> flash attn (split-2)
//   -> merge -> out GEMM.
// ws: 0 xn | 4MB WqkvT | 7MB Wbig | 9MB GH | +64K WmT | +192K Aq | 10MB QK (Bq transient)
//     26MB Vt | 34MB Obuf bf16[4096][1024] | 42MB Opart bf16[2][4096][1024] | 74MB Lpart f32[2][4096][8]

typedef __attribute__((ext_vector_type(8))) short bf16x8;
typedef __attribute__((ext_vector_type(4))) float f32x4;

#define QSCALE 0.18033688011112042f  /* 64^-0.5 * log2(e) */

__device__ __forceinline__ unsigned short f2b(float f) {
    union { float f; unsigned int u; } v; v.f = f;
    unsigned int r = v.u + 0x7fffu + ((v.u >> 16) & 1u);
    return (unsigned short)(r >> 16);
}

__device__ __forceinline__ float b2f(short s) {
    union { float f; unsigned int u; } v;
    v.u = ((unsigned int)(unsigned short)s) << 16;
    return v.f;
}

__device__ __forceinline__ unsigned int cvtpk(float a, float b) {
    union { __hip_bfloat162 h; unsigned int u; } v;
    v.h = __float22bfloat162_rn(make_float2(a, b));
    return v.u;
}

__device__ __forceinline__ void ld16(void* lds, const void* g) {
    __builtin_amdgcn_global_load_lds(
        (__attribute__((address_space(1))) unsigned int*)(g),
        (__attribute__((address_space(3))) unsigned int*)(lds), 16, 0, 0);
}

// ---------------- 1. prep ----------------
// blocks 0..1023   : row L2-norm of x -> xn bf16
// blocks 1024..1279: Wk/Wv 512x512 transposes -> bf16 directly into WqkvT K/V sections
// blocks 1280..1287: Wm transposes -> WmT fp32
// blocks 1288..1415: Bq reshape: Bq[h*512+k][reim*64+d] = Wq_reim[k][h*64+d] (bf16)
__global__ __launch_bounds__(256) void k_prep(
        const float* __restrict__ x, unsigned short* __restrict__ xn,
        const float* __restrict__ Wq_re, const float* __restrict__ Wq_im,
        const float* __restrict__ Wk_re, const float* __restrict__ Wk_im,
        const float* __restrict__ Wv_re, const float* __restrict__ Wv_im,
        const float* __restrict__ Wm_re, const float* __restrict__ Wm_im,
        unsigned short* __restrict__ WqkvT, unsigned short* __restrict__ Bq,
        float* __restrict__ WmT_re, float* __restrict__ WmT_im) {
    __shared__ float tile[64][65];
    if (blockIdx.x < 1024) {
        int row  = blockIdx.x * 4 + (threadIdx.x >> 6);
        int lane = threadIdx.x & 63;
        const float4* xr = (const float4*)(x + (size_t)row * 512);
        float4 a = xr[lane], b = xr[lane + 64];
        float s = a.x*a.x + a.y*a.y + a.z*a.z + a.w*a.w
                + b.x*b.x + b.y*b.y + b.z*b.z + b.w*b.w;
        #pragma unroll
        for (int m = 1; m < 64; m <<= 1) s += __shfl_xor(s, m, 64);
        float inv = 1.0f / sqrtf(s);
        ushort4 o;
        o.x = f2b(a.x*inv); o.y = f2b(a.y*inv); o.z = f2b(a.z*inv); o.w = f2b(a.w*inv);
        *(ushort4*)&xn[(size_t)row*512 + lane*4] = o;
        o.x = f2b(b.x*inv); o.y = f2b(b.y*inv); o.z = f2b(b.z*inv); o.w = f2b(b.w*inv);
        *(ushort4*)&xn[(size_t)row*512 + 256 + lane*4] = o;
        return;
    }
    int bid = blockIdx.x - 1024;
    int tx = threadIdx.x & 63, ty = threadIdx.x >> 6;
    if (bid < 256) {
        int mat = bid >> 6, tl = bid & 63;   // 0=Wk_re,1=Wk_im,2=Wv_re,3=Wv_im
        const float* src = (mat==0)?Wk_re:(mat==1)?Wk_im:(mat==2)?Wv_re:Wv_im;
        int r0 = (tl >> 3) * 64, c0 = (tl & 7) * 64;
        #pragma unroll
        for (int i = 0; i < 16; i++) {
            int r = ty + i*4;
            tile[r][tx] = src[(size_t)(r0 + r)*512 + c0 + tx];
        }
        __syncthreads();
        int sec = 1024 + (mat >> 1)*1024, part = mat & 1;
        #pragma unroll
        for (int i = 0; i < 16; i++) {
            int r = ty + i*4;
            int rr = c0 + r, h = rr >> 6, j = rr & 63;
            WqkvT[(size_t)(sec + h*128 + part*64 + j)*512 + r0 + tx] = f2b(tile[tx][r]);
        }
    } else if (bid < 264) {
        int mat = (bid - 256) >> 2, tl = (bid - 256) & 3;
        const float* src = mat ? Wm_im : Wm_re;
        float* dst = mat ? WmT_im : WmT_re;
        int c0 = tl * 64;
        #pragma unroll
        for (int i = 0; i < 16; i++) {
            int r = ty + i*4;
            tile[r][tx] = src[(size_t)r*256 + c0 + tx];
        }
        __syncthreads();
        #pragma unroll
        for (int i = 0; i < 16; i++) {
            int r = ty + i*4;
            dst[(size_t)(c0 + r)*64 + tx] = tile[tx][r];
        }
    } else {
        int b3 = bid - 264;                  // 0..127
        int mat = b3 >> 6, tl = b3 & 63;
        const float* src = mat ? Wq_im : Wq_re;
        #pragma unroll
        for (int i = 0; i < 16; i++) {
            int idx = tl*4096 + i*256 + threadIdx.x;
            int k = idx >> 9, col = idx & 511;
            int h = col >> 6, d = col & 63;
            Bq[(size_t)(h*512 + k)*128 + mat*64 + d] = f2b(src[(size_t)k*512 + col]);
        }
    }
}

// ---------------- 2. G -> Aq bf16[128][128]; Ht -> GH ----------------
__global__ __launch_bounds__(256) void k_gh(const float* __restrict__ Wm_re, const float* __restrict__ Wm_im,
                                            const float* __restrict__ WmT_re, const float* __restrict__ WmT_im,
                                            const float* __restrict__ Wmi_re, const float* __restrict__ Wmi_im,
                                            float* __restrict__ GH, unsigned short* __restrict__ Aq) {
    int id = blockIdx.x * 256 + threadIdx.x;   // 16384
    int mat = id >> 12;
    int a = (id >> 6) & 63, c = id & 63;       // a wave-uniform, c = lane
    float s = 0.f;
    if (mat < 2) {
        for (int m = 0; m < 256; m++) {
            float ar = Wm_re[a*256+m], ai = Wm_im[a*256+m];   // broadcast
            float br = WmT_re[m*64+c], bi = WmT_im[m*64+c];   // lane-contiguous
            s += (mat == 0) ? (ar*br + ai*bi) : (ai*br - ar*bi);
        }
        float sq = s * QSCALE;
        if (mat == 0) {
            Aq[c*128 + a]           = f2b(sq);
            Aq[(64+c)*128 + 64 + a] = f2b(sq);
        } else {
            Aq[(64+c)*128 + a]      = f2b(sq);
            Aq[c*128 + 64 + a]      = f2b(-sq);
        }
    } else {
        for (int m = 0; m < 256; m++) {
            float ar = Wm_re[a*256+m], ai = Wm_im[a*256+m];
            float br = Wmi_re[m*64+c], bi = Wmi_im[m*64+c];
            s += (mat == 2) ? (ar*br - ai*bi) : (ar*bi + ai*br);
        }
        GH[mat*4096 + c*64 + a] = s;   // store H transposed
    }
}

// ---------------- 3. Wo fold: Wbig [1024][1024] bf16 ----------------
__global__ __launch_bounds__(256) void k_packwo(
        const float* __restrict__ Wo_re,  const float* __restrict__ Wo_im,
        const float* __restrict__ GH, unsigned short* __restrict__ Wbig) {
    int id = blockIdx.x * 256 + threadIdx.x;
    int np = id >> 10, kk = id & 1023;
    int c = np >> 1, p = np & 1;
    int h = kk >> 7, pp = (kk >> 6) & 1, d = kk & 63;
    const float* HrT = GH + 2*4096;
    const float* HiT = GH + 3*4096;
    float s = 0.f;
    if (p == pp) {
        for (int j = 0; j < 64; j++) {
            float hr = HrT[j*64+d], hi = HiT[j*64+d];
            float wr = Wo_re[(size_t)(h*64+j)*512 + c];
            float wi = Wo_im[(size_t)(h*64+j)*512 + c];
            s += hr*wr - hi*wi;
        }
    } else {
        for (int j = 0; j < 64; j++) {
            float hr = HrT[j*64+d], hi = HiT[j*64+d];
            float wr = Wo_re[(size_t)(h*64+j)*512 + c];
            float wi = Wo_im[(size_t)(h*64+j)*512 + c];
            s += hr*wi + hi*wr;
        }
        if (p == 0) s = -s;
    }
    Wbig[(size_t)np*1024 + kk] = f2b(s);
}

// ---------------- 5. GEMM: C = A @ Bt^T, MT x 128 tile, BK=64, async ld16 staging.
// MODE 0: QKV gemm (+fused V^T gemm) -> bf16. MODE 1: out gemm -> fp32. MODE 2: Q-fold -> WqkvT Q-section.
template<int MODE, int MT, int MW>
__global__ __launch_bounds__(256, MW) void k_gemm(
        const unsigned short* __restrict__ Ain, const unsigned short* __restrict__ Btin,
        void* __restrict__ Cout, unsigned short* __restrict__ Vt, int K) {
    __shared__ __align__(16) unsigned short Al[2][MT*32];
    __shared__ __align__(16) unsigned short Bl[2][128*32];
    const int t = threadIdx.x;
    const int wave = t >> 6, lane = t & 63, quad = lane >> 4, l16 = lane & 15;
    const int wr = wave >> 1, wc = wave & 1;

    const unsigned short* A;
    const unsigned short* Bt;
    unsigned short* Cb = nullptr;
    int m0, n0;
    if (MODE == 0) {
        if (blockIdx.y < 16) {
            A = Ain; Bt = Btin;
            m0 = blockIdx.x * 128; n0 = blockIdx.y * 128;
            Cb = (unsigned short*)Cout;
        } else {
            int idx = (blockIdx.y - 16) * 32 + blockIdx.x;
            int b = idx >> 7, mt = (idx >> 4) & 7, nt = idx & 15;
            A  = Btin + 2048*512;
            Bt = Ain + (size_t)b*2048*512;
            m0 = mt * 128; n0 = nt * 128;
            Cb = Vt + (size_t)b*1024*2048;
        }
    } else {
        A = Ain; Bt = Btin;
        m0 = blockIdx.x * MT; n0 = blockIdx.y * 128;
    }

    f32x4 acc[MT/32][4] = {};
    for (int kt = 0; kt < K; kt += 64) {
        #pragma unroll
        for (int kh = 0; kh < 2; kh++)
            #pragma unroll
            for (int i = 0; i < MT/64; i++) {
                int g = t + i*256, r = g >> 2, gr = g & 3;
                ld16(&Al[kh][g*8], &A[(size_t)(m0 + r)*K + kt + kh*32 + gr*8]);
            }
        #pragma unroll
        for (int kh = 0; kh < 2; kh++)
            #pragma unroll
            for (int i = 0; i < 2; i++) {
                int g = t + i*256, r = g >> 2, gr = g & 3;
                ld16(&Bl[kh][g*8], &Bt[(size_t)(n0 + r)*K + kt + kh*32 + gr*8]);
            }
        __syncthreads();
        #pragma unroll
        for (int kh = 0; kh < 2; kh++) {
            bf16x8 af[MT/32], bfr[4];
            #pragma unroll
            for (int rt = 0; rt < MT/32; rt++)
                af[rt] = *(const bf16x8*)&Al[kh][(wr*(MT/2) + rt*16 + l16)*32 + quad*8];
            #pragma unroll
            for (int ct = 0; ct < 4; ct++)
                bfr[ct] = *(const bf16x8*)&Bl[kh][(wc*64 + ct*16 + l16)*32 + quad*8];
            #pragma unroll
            for (int rt = 0; rt < MT/32; rt++)
                #pragma unroll
                for (int ct = 0; ct < 4; ct++)
                    acc[rt][ct] = __builtin_amdgcn_mfma_f32_16x16x32_bf16(af[rt], bfr[ct], acc[rt][ct], 0, 0, 0);
        }
        __syncthreads();
    }
    #pragma unroll
    for (int rt = 0; rt < MT/32; rt++) {
        int row = m0 + wr*(MT/2) + rt*16 + quad*4;
        #pragma unroll
        for (int ct = 0; ct < 4; ct++) {
            int col = n0 + wc*64 + ct*16 + l16;
            if (MODE == 0) {
                unsigned int u01 = cvtpk(acc[rt][ct][0], acc[rt][ct][1]);
                unsigned int u23 = cvtpk(acc[rt][ct][2], acc[rt][ct][3]);
                Cb[(size_t)(row+0)*2048 + col] = (unsigned short)(u01);
                Cb[(size_t)(row+1)*2048 + col] = (unsigned short)(u01 >> 16);
                Cb[(size_t)(row+2)*2048 + col] = (unsigned short)(u23);
                Cb[(size_t)(row+3)*2048 + col] = (unsigned short)(u23 >> 16);
            } else if (MODE == 2) {
                unsigned short* Cq = (unsigned short*)Cout;
                int h = col >> 9, k = col & 511;
                unsigned int u01 = cvtpk(acc[rt][ct][0], acc[rt][ct][1]);
                unsigned int u23 = cvtpk(acc[rt][ct][2], acc[rt][ct][3]);
                Cq[(size_t)(h*128 + row + 0)*512 + k] = (unsigned short)(u01);
                Cq[(size_t)(h*128 + row + 1)*512 + k] = (unsigned short)(u01 >> 16);
                Cq[(size_t)(h*128 + row + 2)*512 + k] = (unsigned short)(u23);
                Cq[(size_t)(h*128 + row + 3)*512 + k] = (unsigned short)(u23 >> 16);
            } else {
                float* C = (float*)Cout;
                #pragma unroll
                for (int r = 0; r < 4; r++)
                    C[(size_t)(row + r)*1024 + col] = acc[rt][ct][r];
            }
        }
    }
}

// ---------------- 6. flash attention: split-2 across blocks, KT=64, K+V LDS dbuf, 1 barrier/iter.
__global__ __launch_bounds__(256, 2) void k_attn(
        const unsigned short* __restrict__ QK,   // [4096][2048]
        const unsigned short* __restrict__ Vt,   // [2048][2048]
        unsigned short* __restrict__ Opart,      // [2][4096][1024] bf16 (normalized per half)
        float* __restrict__ Lpart) {             // [2][4096][8]
    __shared__ __align__(16) unsigned short Kl[2][8192];
    __shared__ __align__(16) unsigned short Vl[2][8192];
    __shared__ __align__(16) unsigned short Pl[4608];

    const int t = threadIdx.x, w = t >> 6, lane = t & 63, quad = lane >> 4, l16 = lane & 15;
    const int quadx = quad ^ ((l16 >> 2) & 3);
    const int bh = blockIdx.x, b = bh >> 3, h = bh & 7;
    const int qb = blockIdx.y & 15, half = blockIdx.y >> 4;
    const int tok0 = b*2048 + qb*128;

    bf16x8 qf[2][4];
    #pragma unroll
    for (int rt = 0; rt < 2; rt++)
        #pragma unroll
        for (int ks = 0; ks < 4; ks++)
            qf[rt][ks] = *(const bf16x8*)&QK[(size_t)(tok0 + w*32 + rt*16 + l16)*2048 + h*128 + ks*32 + quad*8];

    const int grs = (t & 3) ^ ((t >> 4) & 3);
    const unsigned short* kp = QK + (size_t)(b*2048 + half*1024 + (t >> 2))*2048 + 1024 + h*128 + grs*8;
    const unsigned short* vp = Vt + (size_t)(b*1024 + h*128 + (t >> 2))*2048 + half*1024 + grs*8;

    f32x4 Oacc[2][8] = {};
    float ls[2][4] = {};

    #pragma unroll
    for (int i = 0; i < 4; i++) ld16(&Kl[0][(i*256 + t)*8], kp + i*32);
    #pragma unroll
    for (int i = 0; i < 4; i++) ld16(&Vl[0][(i*256 + t)*8], vp + (i & 1)*131072 + (i >> 1)*32);
    __syncthreads();

    for (int it = 0; it < 16; it++) {
        const int cur = it & 1;
        if (it < 15) {
            int kt2 = (it + 1) * 64;
            #pragma unroll
            for (int i = 0; i < 4; i++) ld16(&Kl[cur^1][(i*256 + t)*8], kp + (size_t)kt2*2048 + i*32);
            #pragma unroll
            for (int i = 0; i < 4; i++) ld16(&Vl[cur^1][(i*256 + t)*8], vp + kt2 + (i & 1)*131072 + (i >> 1)*32);
        }

        f32x4 S[2][4] = {};
        #pragma unroll
        for (int ks = 0; ks < 4; ks++) {
            #pragma unroll
            for (int ct = 0; ct < 4; ct++) {
                bf16x8 kf = *(const bf16x8*)&Kl[cur][ks*2048 + (ct*16 + l16)*32 + quadx*8];
                #pragma unroll
                for (int rt = 0; rt < 2; rt++)
                    S[rt][ct] = __builtin_amdgcn_mfma_f32_16x16x32_bf16(qf[rt][ks], kf, S[rt][ct], 0, 0, 0);
            }
        }
        #pragma unroll
        for (int ks2 = 0; ks2 < 2; ks2++) {
            #pragma unroll
            for (int rt = 0; rt < 2; rt++) {
                #pragma unroll
                for (int ct2 = 0; ct2 < 2; ct2++) {
                    int ct = ks2*2 + ct2;
                    float p0 = exp2f(S[rt][ct][0]), p1 = exp2f(S[rt][ct][1]);
                    float p2 = exp2f(S[rt][ct][2]), p3 = exp2f(S[rt][ct][3]);
                    ls[rt][0] += p0; ls[rt][1] += p1; ls[rt][2] += p2; ls[rt][3] += p3;
                    int q = w*32 + rt*16 + quad*4;
                    int base = ct2*16 + l16;
                    unsigned int u01 = cvtpk(p0, p1);
                    unsigned int u23 = cvtpk(p2, p3);
                    Pl[base + (q+0)*36] = (unsigned short)(u01);
                    Pl[base + (q+1)*36] = (unsigned short)(u01 >> 16);
                    Pl[base + (q+2)*36] = (unsigned short)(u23);
                    Pl[base + (q+3)*36] = (unsigned short)(u23 >> 16);
                }
            }
            bf16x8 pf[2];
            #pragma unroll
            for (int rt = 0; rt < 2; rt++)
                pf[rt] = *(const bf16x8*)&Pl[(w*32 + rt*16 + l16)*36 + quad*8];
            #pragma unroll
            for (int dt = 0; dt < 8; dt++) {
                bf16x8 vf = *(const bf16x8*)&Vl[cur][ks2*4096 + (dt*16 + l16)*32 + quadx*8];
                #pragma unroll
                for (int rt = 0; rt < 2; rt++)
                    Oacc[rt][dt] = __builtin_amdgcn_mfma_f32_16x16x32_bf16(pf[rt], vf, Oacc[rt][dt], 0, 0, 0);
            }
        }
        __syncthreads();
    }

    #pragma unroll
    for (int rt = 0; rt < 2; rt++)
        #pragma unroll
        for (int r = 0; r < 4; r++) {
            float s = ls[rt][r];
            #pragma unroll
            for (int m = 1; m < 16; m <<= 1) s += __shfl_xor(s, m, 64);
            ls[rt][r] = s;
        }
    unsigned short* Op = Opart + (size_t)half*4096*1024;
    float* Lp = Lpart + (size_t)half*32768;
    #pragma unroll
    for (int rt = 0; rt < 2; rt++) {
        int q = w*32 + rt*16 + quad*4;
        int tok = tok0 + q;
        float inv[4];
        #pragma unroll
        for (int r = 0; r < 4; r++) inv[r] = 1.0f / ls[rt][r];
        if (l16 == 0) {
            #pragma unroll
            for (int r = 0; r < 4; r++) Lp[(size_t)(tok + r)*8 + h] = ls[rt][r];
        }
        #pragma unroll
        for (int dt = 0; dt < 8; dt++) {
            int col = h*128 + dt*16 + l16;
            #pragma unroll
            for (int r = 0; r < 4; r++)
                Op[(size_t)(tok + r)*1024 + col] = f2b(Oacc[rt][dt][r] * inv[r]);
        }
    }
}

// ---------------- 6b. merge: O = w0*Ohat0 + w1*Ohat1, w_i = l_i/(l0+l1), cast bf16 ----------------
__global__ __launch_bounds__(256) void k_merge(const unsigned short* __restrict__ Opart,
                                               const float* __restrict__ Lpart,
                                               unsigned short* __restrict__ O) {
    int slot = blockIdx.x * 256 + threadIdx.x;   // 524288 slots of 8 cols
    int tok = slot >> 7, colg = slot & 127, h = colg >> 4;
    float l0 = Lpart[(size_t)tok*8 + h];
    float l1 = Lpart[32768 + (size_t)tok*8 + h];
    float inv = 1.0f / (l0 + l1);
    float w0 = l0*inv, w1 = l1*inv;
    size_t off = (size_t)tok*1024 + colg*8;
    bf16x8 a0 = *(const bf16x8*)&Opart[off];
    bf16x8 a1 = *(const bf16x8*)&Opart[4194304 + off];
    float o[8];
    #pragma unroll
    for (int j = 0; j < 8; j++)
        o[j] = w0*b2f(a0[j]) + w1*b2f(a1[j]);
    uint4 uo;
    uo.x = cvtpk(o[0], o[1]); uo.y = cvtpk(o[2], o[3]);
    uo.z = cvtpk(o[4], o[5]); uo.w = cvtpk(o[6], o[7]);
    *(uint4*)&O[off] = uo;
}

extern "C" void kernel_launch(void* const* d_in, const int* in_sizes, int n_in,
                              void* d_out, int out_size, void* d_ws, size_t ws_size,
                              hipStream_t stream) {
    (void)in_sizes; (void)n_in; (void)out_size; (void)ws_size;
    const float* x      = (const float*)d_in[0];
    const float* Wq_re  = (const float*)d_in[1];
    const float* Wq_im  = (const float*)d_in[2];
    const float* Wk_re  = (const float*)d_in[3];
    const float* Wk_im  = (const float*)d_in[4];
    const float* Wv_re  = (const float*)d_in[5];
    const float* Wv_im  = (const float*)d_in[6];
    const float* Wm_re  = (const float*)d_in[7];
    const float* Wm_im  = (const float*)d_in[8];
    const float* Wmi_re = (const float*)d_in[9];
    const float* Wmi_im = (const float*)d_in[10];
    const float* Wo_re  = (const float*)d_in[11];
    const float* Wo_im  = (const float*)d_in[12];

    char* ws = (char*)d_ws;
    unsigned short* xn    = (unsigned short*)(ws);
    unsigned short* WqkvT = (unsigned short*)(ws + (4u << 20));
    unsigned short* Wbig  = (unsigned short*)(ws + (7u << 20));
    float*          GH    = (float*)         (ws + (9u << 20));
    float*          WmT_re= (float*)         (ws + (9u << 20) + (64u << 10));
    float*          WmT_im= (float*)         (ws + (9u << 20) + (128u << 10));
    unsigned short* Aq    = (unsigned short*)(ws + (9u << 20) + (192u << 10));
    unsigned short* QK    = (unsigned short*)(ws + (10u << 20));
    unsigned short* Bq    = (unsigned short*)(ws + (10u << 20));   // transient, consumed pre-gemm0
    unsigned short* Vt    = (unsigned short*)(ws + (26u << 20));
    unsigned short* Obuf  = (unsigned short*)(ws + (34u << 20));
    unsigned short* Opart = (unsigned short*)(ws + (42u << 20));
    float*          Lpart = (float*)         (ws + (74u << 20));

    k_prep         <<<dim3(1416), dim3(256), 0, stream>>>(
        x, xn, Wq_re, Wq_im, Wk_re, Wk_im, Wv_re, Wv_im, Wm_re, Wm_im,
        WqkvT, Bq, WmT_re, WmT_im);
    k_gh           <<<dim3(64),   dim3(256), 0, stream>>>(
        Wm_re, Wm_im, WmT_re, WmT_im, Wmi_re, Wmi_im, GH, Aq);
    k_gemm<2,128,2><<<dim3(1, 32),  dim3(256), 0, stream>>>(Aq, Bq, (void*)WqkvT, nullptr, 128);
    k_packwo       <<<dim3(4096), dim3(256), 0, stream>>>(Wo_re, Wo_im, GH, Wbig);
    k_gemm<0,128,3><<<dim3(32, 24), dim3(256), 0, stream>>>(xn, WqkvT, (void*)QK, Vt, 512);
    k_attn         <<<dim3(16, 32), dim3(256), 0, stream>>>(QK, Vt, Opart, Lpart);
    k_merge        <<<dim3(2048), dim3(256), 0, stream>>>(Opart, Lpart, Obuf);
    k_gemm<1,64,2> <<<dim3(64, 8),  dim3(256), 0, stream>>>(Obuf, Wbig, d_out, nullptr, 1024);
}